// Round 1
// 315.510 us; speedup vs baseline: 1.0577x; 1.0577x over previous
//
#include <hip/hip_runtime.h>

typedef __bf16 bf16x8 __attribute__((ext_vector_type(8)));
typedef __bf16 bf16x4 __attribute__((ext_vector_type(4)));
typedef float f32x4 __attribute__((ext_vector_type(4)));

typedef const __attribute__((address_space(1))) void* gas_t;
typedef __attribute__((address_space(3))) void* las_t;

static constexpr int DIM = 2048;
static constexpr size_t MAT = (size_t)DIM * DIM;  // 4194304 elements

__device__ __forceinline__ float sigmoidf_(float x) { return 1.f / (1.f + __expf(-x)); }

// ---------------------------------------------------------------------------
// fp32 -> bf16 conversion for X, Wq, Wk, Wv, Wo  (grid: (4096, 5), 256 thr)
// ---------------------------------------------------------------------------
__global__ void cvt_kernel(const float* __restrict__ x, const float* __restrict__ wq,
                           const float* __restrict__ wk, const float* __restrict__ wv,
                           const float* __restrict__ wo, __bf16* __restrict__ dst) {
  const float* s;
  switch (blockIdx.y) {
    case 0: s = x; break;
    case 1: s = wq; break;
    case 2: s = wk; break;
    case 3: s = wv; break;
    default: s = wo; break;
  }
  __bf16* d = dst + (size_t)blockIdx.y * MAT;
  size_t i = ((size_t)blockIdx.x * 256 + threadIdx.x) * 4;
  float4 v = *(const float4*)(s + i);
  bf16x4 ov;
  ov[0] = (__bf16)v.x; ov[1] = (__bf16)v.y; ov[2] = (__bf16)v.z; ov[3] = (__bf16)v.w;
  *(bf16x4*)(d + i) = ov;
}

// ---------------------------------------------------------------------------
// m97-style 128x128x32 bf16 GEMM body: C = A * B^T  (+bias, scale)
// A: [M x 2048] bf16 row-major, B: [N x 2048] bf16 row-major.
// Tile = 128 rows x 32 k x 2B = 8 KiB; 256 thr x 16 B = 4 KiB/iter -> i<2.
// ---------------------------------------------------------------------------
template <bool F32OUT>
__device__ __forceinline__ void gemm128(const __bf16* __restrict__ A, const __bf16* __restrict__ B,
                                        const float* __restrict__ bias, bool bias_row, float scale,
                                        void* __restrict__ Cout, int mtile, int ntile,
                                        __bf16* Asm, __bf16* Bsm) {
  const int t = threadIdx.x, lane = t & 63, w = t >> 6;
  const int wrow = (w >> 1) * 64, wcol = (w & 1) * 64;
  const int rbase = mtile * 128, cbase = ntile * 128;
  f32x4 acc[4][4] = {};

  for (int k0 = 0; k0 < DIM; k0 += 32) {
    __syncthreads();  // previous iteration's LDS reads complete
#pragma unroll
    for (int i = 0; i < 2; ++i) {  // (was i<4: overflowed 8KiB tile -> corrupted Bsm)
      const int o = i * 4096 + w * 1024 + lane * 16;  // byte offset in 128x32 bf16 tile
      const int r = o >> 6;                           // row 0..127
      const int ke = (o & 63) >> 1;                   // element offset in row (0,8,16,24)
      __builtin_amdgcn_global_load_lds((gas_t)(A + (size_t)(rbase + r) * DIM + k0 + ke),
                                       (las_t)(Asm + (o >> 1)), 16, 0, 0);
      __builtin_amdgcn_global_load_lds((gas_t)(B + (size_t)(cbase + r) * DIM + k0 + ke),
                                       (las_t)(Bsm + (o >> 1)), 16, 0, 0);
    }
    __syncthreads();  // compiler drains vmcnt before barrier

    bf16x8 af[4], bf[4];
#pragma unroll
    for (int i = 0; i < 4; ++i)
      af[i] = *(const bf16x8*)(Asm + (wrow + i * 16 + (lane & 15)) * 32 + (lane >> 4) * 8);
#pragma unroll
    for (int j = 0; j < 4; ++j)
      bf[j] = *(const bf16x8*)(Bsm + (wcol + j * 16 + (lane & 15)) * 32 + (lane >> 4) * 8);
#pragma unroll
    for (int i = 0; i < 4; ++i)
#pragma unroll
      for (int j = 0; j < 4; ++j)
        acc[i][j] = __builtin_amdgcn_mfma_f32_16x16x32_bf16(af[i], bf[j], acc[i][j], 0, 0, 0);
  }

  // epilogue: C/D layout col = lane&15, row = (lane>>4)*4 + r
#pragma unroll
  for (int i = 0; i < 4; ++i)
#pragma unroll
    for (int j = 0; j < 4; ++j)
#pragma unroll
      for (int r = 0; r < 4; ++r) {
        const int row = rbase + wrow + i * 16 + (lane >> 4) * 4 + r;
        const int col = cbase + wcol + j * 16 + (lane & 15);
        float v = acc[i][j][r] + (bias_row ? bias[row] : bias[col]);
        v *= scale;
        if (F32OUT)
          ((float*)Cout)[(size_t)row * DIM + col] = v;
        else
          ((__bf16*)Cout)[(size_t)row * DIM + col] = (__bf16)v;
      }
}

// ---------------------------------------------------------------------------
// Fused QKV projections. grid (48,16): sel = x>>4 picks Q / K / V^T.
// Q = (X Wq^T + bq) * alpha   (alpha = (1 - 0.1 sig(justice))/sqrt(128))
// K = X Wk^T + bk
// V^T = Wv X^T + bv[row]      (transposed so attention can global_load_lds it)
// ---------------------------------------------------------------------------
__global__ __launch_bounds__(256, 2) void qkv_kernel(
    const __bf16* __restrict__ Xb, const __bf16* __restrict__ Wqb, const __bf16* __restrict__ Wkb,
    const __bf16* __restrict__ Wvb, const float* __restrict__ bq, const float* __restrict__ bk,
    const float* __restrict__ bv, const float* __restrict__ jgate, __bf16* __restrict__ Qo,
    __bf16* __restrict__ Ko, __bf16* __restrict__ Vto) {
  __shared__ __bf16 Asm[128 * 32];
  __shared__ __bf16 Bsm[128 * 32];
  const int sel = blockIdx.x >> 4, nt = blockIdx.x & 15, mt = blockIdx.y;
  const __bf16 *A, *B;
  const float* bias;
  __bf16* C;
  bool brow = false;
  float sc = 1.f;
  if (sel == 0) {
    A = Xb; B = Wqb; bias = bq; C = Qo;
    sc = (1.f - 0.1f * sigmoidf_(jgate[0])) * 0.08838834764831843f;  // 1/sqrt(128)
  } else if (sel == 1) {
    A = Xb; B = Wkb; bias = bk; C = Ko;
  } else {
    A = Wvb; B = Xb; bias = bv; C = Vto; brow = true;
  }
  gemm128<false>(A, B, bias, brow, sc, C, mt, nt, Asm, Bsm);
}

// ---------------------------------------------------------------------------
// Output projection: out = Ab Wo^T + bo  (fp32 out)
// ---------------------------------------------------------------------------
__global__ __launch_bounds__(256, 2) void outproj_kernel(const __bf16* __restrict__ Ab,
                                                         const __bf16* __restrict__ Wob,
                                                         const float* __restrict__ bo,
                                                         float* __restrict__ Cout) {
  __shared__ __bf16 Asm[128 * 32];
  __shared__ __bf16 Bsm[128 * 32];
  gemm128<true>(Ab, Wob, bo, false, 1.f, Cout, blockIdx.y, blockIdx.x, Asm, Bsm);
}

// ---------------------------------------------------------------------------
// Flash attention. grid (16 qtiles, 16 heads), 512 threads = 8 waves.
// Each wave owns 16 query rows; Q frags live in registers the whole kernel.
//
// This revision vs prior:
//  * K/V double-buffered in LDS (2x16 KiB each); next tile's global_load_lds
//    issued BEFORE computing the current tile, so the vmcnt(0) drain at the
//    single per-tile barrier waits on loads that had a full QK+softmax+PV
//    phase to land (T3 "minimum 2-phase").
//  * Mid-loop barrier removed: Ps is wave-private (each wave reads only the
//    region it wrote; same-wave LDS ordering via lgkmcnt). 3 -> 1 barrier/tile.
//  * K/V rows are 64 B (half the 128 B bank cycle) -> the old linear layout
//    was an 8-way bank conflict on every ds_read_b128. Fixed with the
//    both-sides XOR swizzle (rule #21): LDS destination stays LINEAR
//    (global_load_lds requirement), the per-lane GLOBAL source address is
//    pre-swizzled with o ^= ((o>>7)&3)<<4 (slot ^= row bits 1..2), and the
//    read side applies the same XOR. Each 16-lane phase then covers all 8
//    four-bank groups exactly twice -> 2-way, free per m136.
// ---------------------------------------------------------------------------
__global__ __launch_bounds__(512) void attn_kernel(const __bf16* __restrict__ Q,
                                                   const __bf16* __restrict__ Kg,
                                                   const __bf16* __restrict__ VT,
                                                   const float* __restrict__ ogate,
                                                   __bf16* __restrict__ O) {
  __shared__ __bf16 Ks[2][4 * 64 * 32];   // 2 x 16 KiB, layout [c][key][32] (swizzled slots)
  __shared__ __bf16 Vs[2][2 * 128 * 32];  // 2 x 16 KiB, layout [cc][d][32] (swizzled slots)
  __shared__ __bf16 Ps[8 * 16 * 72];      // 18 KiB, padded stride 72 (2-way max)
  const int t = threadIdx.x, lane = t & 63, w = t >> 6;
  const int h = blockIdx.y, qt = blockIdx.x;
  const float beta = sigmoidf_(ogate[0]) * 0.05f / 2048.0f;

  // per-lane swizzled 8-elem slot offset for K/V reads:
  // slot' = (lane>>4) ^ (row bits 1..2), row = *16 + (lane&15)
  const int rs8 = (((lane >> 4) ^ ((lane >> 1) & 3)) & 3) * 8;

  const int qrow = qt * 128 + w * 16 + (lane & 15);
  bf16x8 qf[4];
#pragma unroll
  for (int c = 0; c < 4; ++c)
    qf[c] = *(const bf16x8*)(Q + (size_t)qrow * DIM + h * 128 + c * 32 + (lane >> 4) * 8);

  f32x4 oacc[8] = {};
  float m_r[4], l_r[4];
#pragma unroll
  for (int r = 0; r < 4; ++r) { m_r[r] = -1e30f; l_r[r] = 0.f; }

  // stage tile kt into buffer buf (LDS dest linear, global source pre-swizzled)
  auto stage = [&](int buf, int kt) {
#pragma unroll
    for (int i = 0; i < 2; ++i) {
      const int o = i * 8192 + w * 1024 + lane * 16;   // linear LDS byte offset
      const int oz = o ^ (((o >> 7) & 3) << 4);        // swizzled logical address
      const int ke = (oz & 63) >> 1;                   // element offset in 32-wide row
      // K tile: [c][key][32]
      const int c = oz >> 12, key = (oz & 4095) >> 6;
      __builtin_amdgcn_global_load_lds(
          (gas_t)(Kg + (size_t)(kt + key) * DIM + h * 128 + c * 32 + ke),
          (las_t)(&Ks[buf][0] + (o >> 1)), 16, 0, 0);
      // V^T tile: [cc][d][32]
      const int cc = oz >> 13, d = (oz & 8191) >> 6;
      __builtin_amdgcn_global_load_lds(
          (gas_t)(VT + (size_t)(h * 128 + d) * DIM + kt + cc * 32 + ke),
          (las_t)(&Vs[buf][0] + (o >> 1)), 16, 0, 0);
    }
  };

  stage(0, 0);
  int p = 0;
  for (int kt = 0; kt < 2048; kt += 64) {
    __syncthreads();  // buf[p] staged (vmcnt drained here); buf[p^1] reads from t-1 done
    if (kt + 64 < 2048) stage(p ^ 1, kt + 64);  // prefetch next tile; drains at NEXT barrier

    // QK^T: s[j] = 16q x 16key block j
    f32x4 s[4];
#pragma unroll
    for (int j = 0; j < 4; ++j) {
      f32x4 a = {};
#pragma unroll
      for (int c = 0; c < 4; ++c) {
        bf16x8 kf = *(const bf16x8*)(&Ks[p][0] + c * 2048 + (j * 16 + (lane & 15)) * 32 + rs8);
        a = __builtin_amdgcn_mfma_f32_16x16x32_bf16(qf[c], kf, a, 0, 0, 0);
      }
      s[j] = a;
    }
    // per-key position bias (the only gate term that survives softmax besides alpha)
#pragma unroll
    for (int j = 0; j < 4; ++j) {
      const float pb = beta * (float)(kt + j * 16 + (lane & 15));
#pragma unroll
      for (int r = 0; r < 4; ++r) s[j][r] += pb;
    }
    // row max over 64 keys: regs then 16-lane butterfly
    float rmax[4];
#pragma unroll
    for (int r = 0; r < 4; ++r)
      rmax[r] = fmaxf(fmaxf(s[0][r], s[1][r]), fmaxf(s[2][r], s[3][r]));
#pragma unroll
    for (int msk = 1; msk < 16; msk <<= 1)
#pragma unroll
      for (int r = 0; r < 4; ++r) rmax[r] = fmaxf(rmax[r], __shfl_xor(rmax[r], msk, 64));

    float al[4];
#pragma unroll
    for (int r = 0; r < 4; ++r) {
      const float mn = fmaxf(m_r[r], rmax[r]);
      al[r] = __expf(m_r[r] - mn);
      m_r[r] = mn;
    }
#pragma unroll
    for (int j = 0; j < 4; ++j)
#pragma unroll
      for (int r = 0; r < 4; ++r) s[j][r] = __expf(s[j][r] - m_r[r]);

    float rs[4];
#pragma unroll
    for (int r = 0; r < 4; ++r) rs[r] = (s[0][r] + s[1][r]) + (s[2][r] + s[3][r]);
#pragma unroll
    for (int msk = 1; msk < 16; msk <<= 1)
#pragma unroll
      for (int r = 0; r < 4; ++r) rs[r] += __shfl_xor(rs[r], msk, 64);
#pragma unroll
    for (int r = 0; r < 4; ++r) l_r[r] = l_r[r] * al[r] + rs[r];
#pragma unroll
    for (int d = 0; d < 8; ++d)
#pragma unroll
      for (int r = 0; r < 4; ++r) oacc[d][r] *= al[r];

    // write P (C-layout -> row-major [16 q][64 key], stride 72).
    // Wave-private region: no barrier needed before the PV reads below
    // (same-wave LDS ordering is enforced by lgkmcnt).
    {
      __bf16* pw = Ps + w * 1152;
#pragma unroll
      for (int j = 0; j < 4; ++j)
#pragma unroll
        for (int r = 0; r < 4; ++r)
          pw[((lane >> 4) * 4 + r) * 72 + j * 16 + (lane & 15)] = (__bf16)s[j][r];
    }

    // PV: oacc[d] += P(16x64) * V(64 x 16d-block)
#pragma unroll
    for (int cc = 0; cc < 2; ++cc) {
      bf16x8 pa = *(const bf16x8*)(Ps + w * 1152 + (lane & 15) * 72 + cc * 32 + (lane >> 4) * 8);
#pragma unroll
      for (int d = 0; d < 8; ++d) {
        bf16x8 vf = *(const bf16x8*)(&Vs[p][0] + cc * 4096 + (d * 16 + (lane & 15)) * 32 + rs8);
        oacc[d] = __builtin_amdgcn_mfma_f32_16x16x32_bf16(pa, vf, oacc[d], 0, 0, 0);
      }
    }
    p ^= 1;
  }

  // epilogue: normalize and store bf16 attention output [S][2048]
#pragma unroll
  for (int d = 0; d < 8; ++d)
#pragma unroll
    for (int r = 0; r < 4; ++r) {
      const int row = qt * 128 + w * 16 + (lane >> 4) * 4 + r;
      const int col = h * 128 + d * 16 + (lane & 15);
      O[(size_t)row * DIM + col] = (__bf16)(oacc[d][r] / l_r[r]);
    }
}

// ---------------------------------------------------------------------------
extern "C" void kernel_launch(void* const* d_in, const int* in_sizes, int n_in,
                              void* d_out, int out_size, void* d_ws, size_t ws_size,
                              hipStream_t stream) {
  const float* X  = (const float*)d_in[0];
  const float* Wq = (const float*)d_in[1];
  const float* bq = (const float*)d_in[2];
  const float* Wk = (const float*)d_in[3];
  const float* bk = (const float*)d_in[4];
  const float* Wv = (const float*)d_in[5];
  const float* bv = (const float*)d_in[6];
  const float* Wo = (const float*)d_in[7];
  const float* bo = (const float*)d_in[8];
  // gates: truth(9), balance(10), order(11), justice(12), harmony(13)
  const float* order_g   = (const float*)d_in[11];
  const float* justice_g = (const float*)d_in[12];

  __bf16* wsb = (__bf16*)d_ws;
  __bf16* Xb  = wsb + 0 * MAT;
  __bf16* Wqb = wsb + 1 * MAT;
  __bf16* Wkb = wsb + 2 * MAT;
  __bf16* Wvb = wsb + 3 * MAT;
  __bf16* Wob = wsb + 4 * MAT;
  __bf16* Qb  = wsb + 5 * MAT;
  __bf16* Kb  = wsb + 6 * MAT;
  __bf16* VTb = wsb + 7 * MAT;
  __bf16* Ab  = Xb;  // alias: X is dead after qkv_kernel (keeps ws use at 64 MB)

  cvt_kernel<<<dim3(4096, 5), 256, 0, stream>>>(X, Wq, Wk, Wv, Wo, wsb);
  qkv_kernel<<<dim3(48, 16), 256, 0, stream>>>(Xb, Wqb, Wkb, Wvb, bq, bk, bv, justice_g,
                                               Qb, Kb, VTb);
  attn_kernel<<<dim3(16, 16), 512, 0, stream>>>(Qb, Kb, VTb, order_g, Ab);
  outproj_kernel<<<dim3(16, 16), 256, 0, stream>>>(Ab, Wob, bo, (float*)d_out);
}